// Round 4
// baseline (14861.497 us; speedup 1.0000x reference)
//
#include <hip/hip_runtime.h>
#include <hip/hip_fp16.h>
#include <cstdint>
#include <cstddef>

// Problem constants (match reference)
#define Bq 64
#define Tq 512
#define Sq 4
#define Hq 512
#define Vq 10000

typedef float floatx2 __attribute__((ext_vector_type(2)));

// ln(1024): E is stored as fp8 of (1024 * softmax(tran)) so entries land in
// e4m3's normal range [0.037, 40] (unscaled they'd sit at the subnormal
// granularity 2^-9 and quantize catastrophically).
#define LOG_E_SCALE 6.931471805599453f

// ---------------------------------------------------------------------------
// K1: Z[r] = logsumexp_v U[r, :]  for r in [0, S*H)   (rows of length V)
// ---------------------------------------------------------------------------
__global__ __launch_bounds__(256) void k_row_lse(const float* __restrict__ U,
                                                 float* __restrict__ Z) {
  const int r = blockIdx.x;
  const int tid = threadIdx.x;
  const int lane = tid & 63, wid = tid >> 6;
  __shared__ float sred[8];
  const float4* row = (const float4*)(U + (size_t)r * Vq);  // V=10000 -> 2500 float4
  float m = -1e30f;
  for (int i = tid; i < Vq / 4; i += 256) {
    float4 x = row[i];
    m = fmaxf(fmaxf(m, fmaxf(x.x, x.y)), fmaxf(x.z, x.w));
  }
#pragma unroll
  for (int o = 32; o; o >>= 1) m = fmaxf(m, __shfl_xor(m, o));
  if (lane == 0) sred[wid] = m;
  __syncthreads();
  const float M = fmaxf(fmaxf(sred[0], sred[1]), fmaxf(sred[2], sred[3]));
  float s = 0.f;
  for (int i = tid; i < Vq / 4; i += 256) {
    float4 x = row[i];
    s += expf(x.x - M) + expf(x.y - M) + expf(x.z - M) + expf(x.w - M);
  }
#pragma unroll
  for (int o = 32; o; o >>= 1) s += __shfl_xor(s, o);
  if (lane == 0) sred[4 + wid] = s;
  __syncthreads();
  if (tid == 0) {
    Z[r] = M + logf(sred[4] + sred[5] + sred[6] + sred[7]);
  }
}

// ---------------------------------------------------------------------------
// K2: C[h] = 0.25 * sum_s Z[s*H + h]
// ---------------------------------------------------------------------------
__global__ __launch_bounds__(512) void k_cvec(const float* __restrict__ Z,
                                              float* __restrict__ C) {
  const int h = threadIdx.x;
  C[h] = 0.25f * (Z[h] + Z[Hq + h] + Z[2 * Hq + h] + Z[3 * Hq + h]);
}

// ---------------------------------------------------------------------------
// K3: E8[j,k] = fp8_e4m3( 1024 * softmax_k(tran[j,:]) )   (packed 4/word)
// ---------------------------------------------------------------------------
__global__ __launch_bounds__(512) void k_tran_softmax(const float* __restrict__ tr,
                                                      unsigned int* __restrict__ E8w) {
  const int j = blockIdx.x, tid = threadIdx.x;
  const int lane = tid & 63, wid = tid >> 6;
  __shared__ float sred[16];
  __shared__ float p[Hq];
  const float t = tr[j * Hq + tid];
  float m = t;
#pragma unroll
  for (int o = 32; o; o >>= 1) m = fmaxf(m, __shfl_xor(m, o));
  if (lane == 0) sred[wid] = m;
  __syncthreads();
  float M = sred[0];
#pragma unroll
  for (int q = 1; q < 8; ++q) M = fmaxf(M, sred[q]);
  const float e = expf(t - M);
  float s = e;
#pragma unroll
  for (int o = 32; o; o >>= 1) s += __shfl_xor(s, o);
  if (lane == 0) sred[8 + wid] = s;
  __syncthreads();
  float S = 0.f;
#pragma unroll
  for (int q = 0; q < 8; ++q) S += sred[8 + q];
  p[tid] = 1024.0f * e / S;
  __syncthreads();
  if (tid < 128) {
    int w0 = __builtin_amdgcn_cvt_pk_fp8_f32(p[4 * tid], p[4 * tid + 1], 0, false);
    w0 = __builtin_amdgcn_cvt_pk_fp8_f32(p[4 * tid + 2], p[4 * tid + 3], w0, true);
    E8w[j * 128 + tid] = (unsigned int)w0;
  }
}

// ---------------------------------------------------------------------------
// K4: transpose U (S,H,V) -> UT (S,V,H) so per-(s,v) h-vectors are contiguous
// ---------------------------------------------------------------------------
__global__ __launch_bounds__(256) void k_transpose(const float* __restrict__ U,
                                                   float* __restrict__ UT) {
  __shared__ float tile[32][33];
  const int s = blockIdx.z;
  const int v0 = blockIdx.x * 32, h0 = blockIdx.y * 32;
  const int tx = threadIdx.x, ty = threadIdx.y;  // 32 x 8
#pragma unroll
  for (int q = 0; q < 4; ++q) {
    const int h = h0 + ty + q * 8;
    const int v = v0 + tx;
    if (v < Vq) tile[ty + q * 8][tx] = U[((size_t)s * Hq + h) * Vq + v];
  }
  __syncthreads();
#pragma unroll
  for (int q = 0; q < 4; ++q) {
    const int v = v0 + ty + q * 8;
    if (v < Vq) UT[((size_t)s * Vq + v) * Hq + h0 + tx] = tile[tx][ty + q * 8];
  }
}

// ---------------------------------------------------------------------------
// Emission for one (b,t), state k:  0.25*sum_s table[s][obs_s][k] - C[k]
// ---------------------------------------------------------------------------
__device__ __forceinline__ float emis_at(const float* __restrict__ U,
                                         const float* __restrict__ UT,
                                         const float* __restrict__ C,
                                         const int* __restrict__ ob, int k,
                                         int use_ut) {
  float e;
  if (use_ut) {
    e = UT[((size_t)0 * Vq + ob[0]) * Hq + k] +
        UT[((size_t)1 * Vq + ob[1]) * Hq + k] +
        UT[((size_t)2 * Vq + ob[2]) * Hq + k] +
        UT[((size_t)3 * Vq + ob[3]) * Hq + k];
  } else {
    e = U[((size_t)0 * Hq + k) * Vq + ob[0]] +
        U[((size_t)1 * Hq + k) * Vq + ob[1]] +
        U[((size_t)2 * Hq + k) * Vq + ob[2]] +
        U[((size_t)3 * Hq + k) * Vq + ob[3]];
  }
  return 0.25f * e - C[k];
}

// ---------------------------------------------------------------------------
// K5: forward recursion. One workgroup per batch element b; 512 threads.
// R1-R3 counters showed the per-step matvec is bound by E load-instruction
// count (time tracked #loads, not bytes: f16 16B and fp8 8B both 4.6us/step).
// Fix: E is CONSTANT across steps and only 512B/thread -> preload the whole
// fp8 E into registers (32 x uint4 = 128 VGPR/thread across 512 threads).
// Per step the matvec is then pure VALU+LDS, zero global loads:
//   thread (g = tid>>5, i = tid&31) owns j in [32g,32g+32), k in [16i,16i+16)
//   B1: publish per-wave max of alpha -> M
//   B2: publish w_j = exp(alpha_j - M)
//   unrolled 32-iter: wj = w[32g+jj] (LDS broadcast), 8 cvt_pk_f32_fp8 +
//   16 v_fmac into acc[16]
//   B3: publish partials part2[g][q][i] (padded float4 layout, ~4-way banks);
//   alpha_k = em + M + log(sum_g part) - ln(1024)
// Early-exits at t = lengths[b]-1, then out[b] = logsumexp_k alpha.
// ---------------------------------------------------------------------------
__global__ __launch_bounds__(512) void k_forward(const int* __restrict__ obs,
                                                 const int* __restrict__ lengths,
                                                 const float* __restrict__ U,
                                                 const float* __restrict__ UT,
                                                 const float* __restrict__ C,
                                                 const unsigned int* __restrict__ E8,
                                                 const float* __restrict__ pri,
                                                 float* __restrict__ out,
                                                 int use_ut) {
  const int b = blockIdx.x;
  const int tid = threadIdx.x;           // = state k it owns for alpha
  const int lane = tid & 63, wid = tid >> 6;
  const int L = lengths[b];

  __shared__ float w[Hq];                // 2 KB
  __shared__ float4 part2[16][4][33];    // [g][q][i], i-padded: 33.8 KB
  __shared__ float red[16];

  const int g = tid >> 5;   // j-group 0..15 (each covers 32 j)
  const int i = tid & 31;   // k-16-tuple: k = 16*i .. 16*i+15

  // Preload this thread's E slice into registers: rows 32g..32g+31,
  // 16 fp8 per row starting at k=16i. uint4 = 16 fp8.
  const uint4* E8v4 = (const uint4*)E8;  // row j = 32 uint4
  uint4 er[32];
#pragma unroll
  for (int jj = 0; jj < 32; ++jj) {
    er[jj] = E8v4[(size_t)(32 * g + jj) * 32 + i];
  }

  // invariant decomposition for the final partial-sum read: k = tid
  const int ip = tid >> 4, qq = (tid >> 2) & 3, rr = tid & 3;

  // t = 0
  const int* ob0 = obs + ((size_t)b * Tq + 0) * Sq;
  float a = emis_at(U, UT, C, ob0, tid, use_ut) + pri[tid];

  for (int t = 1; t < L; ++t) {
    // issue emission gathers early (independent of the reduce/matvec)
    const int* obt = obs + ((size_t)b * Tq + t) * Sq;
    const float emt = emis_at(U, UT, C, obt, tid, use_ut);

    // block max of alpha
    float m = a;
#pragma unroll
    for (int o = 32; o; o >>= 1) m = fmaxf(m, __shfl_xor(m, o));
    if (lane == 0) red[wid] = m;
    __syncthreads();  // B1: red published; prev-iter part2 reads complete
    float M = red[0];
#pragma unroll
    for (int q = 1; q < 8; ++q) M = fmaxf(M, red[q]);

    w[tid] = expf(a - M);
    __syncthreads();  // B2: w published

    // matvec from registers: k = 16i..16i+15 over j in [32g, 32g+32)
    float acc[16];
#pragma unroll
    for (int q = 0; q < 16; ++q) acc[q] = 0.f;
    const float* wg = &w[32 * g];
#pragma unroll
    for (int jj = 0; jj < 32; ++jj) {
      const float wj = wg[jj];
      const uint4 e = er[jj];
      floatx2 p;
      p = __builtin_amdgcn_cvt_pk_f32_fp8(e.x, false);
      acc[0] += wj * p.x;  acc[1] += wj * p.y;
      p = __builtin_amdgcn_cvt_pk_f32_fp8(e.x, true);
      acc[2] += wj * p.x;  acc[3] += wj * p.y;
      p = __builtin_amdgcn_cvt_pk_f32_fp8(e.y, false);
      acc[4] += wj * p.x;  acc[5] += wj * p.y;
      p = __builtin_amdgcn_cvt_pk_f32_fp8(e.y, true);
      acc[6] += wj * p.x;  acc[7] += wj * p.y;
      p = __builtin_amdgcn_cvt_pk_f32_fp8(e.z, false);
      acc[8] += wj * p.x;  acc[9] += wj * p.y;
      p = __builtin_amdgcn_cvt_pk_f32_fp8(e.z, true);
      acc[10] += wj * p.x; acc[11] += wj * p.y;
      p = __builtin_amdgcn_cvt_pk_f32_fp8(e.w, false);
      acc[12] += wj * p.x; acc[13] += wj * p.y;
      p = __builtin_amdgcn_cvt_pk_f32_fp8(e.w, true);
      acc[14] += wj * p.x; acc[15] += wj * p.y;
    }
#pragma unroll
    for (int q = 0; q < 4; ++q) {
      part2[g][q][i] = float4{acc[4 * q], acc[4 * q + 1], acc[4 * q + 2],
                              acc[4 * q + 3]};
    }
    __syncthreads();  // B3: part2 published; w reads complete

    // ssum over the 16 j-groups for k = tid = 16*ip + 4*qq + rr
    float ssum = 0.f;
#pragma unroll
    for (int gg = 0; gg < 16; ++gg) {
      const float* p4 = (const float*)&part2[gg][qq][ip];
      ssum += p4[rr];
    }
    a = emt + M + logf(ssum) - LOG_E_SCALE;
    // part2 reads above happen-before next B1 -> next part2 write (post-B2)
  }

  // out[b] = logsumexp_k a
  float m = a;
#pragma unroll
  for (int o = 32; o; o >>= 1) m = fmaxf(m, __shfl_xor(m, o));
  if (lane == 0) red[wid] = m;
  __syncthreads();
  float M = red[0];
#pragma unroll
  for (int q = 1; q < 8; ++q) M = fmaxf(M, red[q]);
  float e = expf(a - M);
#pragma unroll
  for (int o = 32; o; o >>= 1) e += __shfl_xor(e, o);
  if (lane == 0) red[8 + wid] = e;
  __syncthreads();
  if (tid == 0) {
    float S = 0.f;
#pragma unroll
    for (int q = 0; q < 8; ++q) S += red[8 + q];
    out[b] = M + logf(S);
  }
}

// ---------------------------------------------------------------------------
// Workspace layout (bytes):
//   E8  : [0, 262144)                 fp8 1024*softmax(tran)  256 KB
//   Z   : [262144, 270336)            per-(s,h) row LSE       8 KB
//   C   : [270336, 272384)            emission constant       2 KB
//   UT  : [272384, 272384+81920000)   transposed table        81.9 MB
// ---------------------------------------------------------------------------
extern "C" void kernel_launch(void* const* d_in, const int* in_sizes, int n_in,
                              void* d_out, int out_size, void* d_ws,
                              size_t ws_size, hipStream_t stream) {
  const int* obs = (const int*)d_in[0];
  const int* lengths = (const int*)d_in[1];
  const float* U = (const float*)d_in[2];       // unnormalized_emis (S,H,V)
  const float* tran = (const float*)d_in[3];    // unnormalized_tran (H,H)
  const float* pri = (const float*)d_in[4];     // log_state_priors (H,)
  float* out = (float*)d_out;

  char* ws = (char*)d_ws;
  unsigned int* E8 = (unsigned int*)ws;
  float* Z = (float*)(ws + 262144);
  float* C = (float*)(ws + 270336);
  float* UT = (float*)(ws + 272384);

  const size_t need_ut_bytes = 272384ull + 81920000ull;
  const int use_ut = (ws_size >= need_ut_bytes) ? 1 : 0;

  k_row_lse<<<Sq * Hq, 256, 0, stream>>>(U, Z);
  k_cvec<<<1, 512, 0, stream>>>(Z, C);
  k_tran_softmax<<<Hq, 512, 0, stream>>>(tran, E8);
  if (use_ut) {
    dim3 grid((Vq + 31) / 32, Hq / 32, Sq);
    k_transpose<<<grid, dim3(32, 8), 0, stream>>>(U, UT);
  }
  k_forward<<<Bq, 512, 0, stream>>>(obs, lengths, U, UT, C, E8, pri, out,
                                    use_ut);
}

// Round 6
// 13652.107 us; speedup vs baseline: 1.0886x; 1.0886x over previous
//
#include <hip/hip_runtime.h>
#include <hip/hip_fp16.h>
#include <cstdint>
#include <cstddef>

// Problem constants (match reference)
#define Bq 64
#define Tq 512
#define Sq 4
#define Hq 512
#define Vq 10000

typedef float floatx2 __attribute__((ext_vector_type(2)));

// ln(1024): E is stored as fp8 of (1024 * softmax(tran)) so entries land in
// e4m3's normal range [0.037, 40] (unscaled they'd sit at the subnormal
// granularity 2^-9 and quantize catastrophically).
#define LOG_E_SCALE 6.931471805599453f

// ---------------------------------------------------------------------------
// K1: Z[r] = logsumexp_v U[r, :]  for r in [0, S*H)   (rows of length V)
// ---------------------------------------------------------------------------
__global__ __launch_bounds__(256) void k_row_lse(const float* __restrict__ U,
                                                 float* __restrict__ Z) {
  const int r = blockIdx.x;
  const int tid = threadIdx.x;
  const int lane = tid & 63, wid = tid >> 6;
  __shared__ float sred[8];
  const float4* row = (const float4*)(U + (size_t)r * Vq);  // V=10000 -> 2500 float4
  float m = -1e30f;
  for (int i = tid; i < Vq / 4; i += 256) {
    float4 x = row[i];
    m = fmaxf(fmaxf(m, fmaxf(x.x, x.y)), fmaxf(x.z, x.w));
  }
#pragma unroll
  for (int o = 32; o; o >>= 1) m = fmaxf(m, __shfl_xor(m, o));
  if (lane == 0) sred[wid] = m;
  __syncthreads();
  const float M = fmaxf(fmaxf(sred[0], sred[1]), fmaxf(sred[2], sred[3]));
  float s = 0.f;
  for (int i = tid; i < Vq / 4; i += 256) {
    float4 x = row[i];
    s += expf(x.x - M) + expf(x.y - M) + expf(x.z - M) + expf(x.w - M);
  }
#pragma unroll
  for (int o = 32; o; o >>= 1) s += __shfl_xor(s, o);
  if (lane == 0) sred[4 + wid] = s;
  __syncthreads();
  if (tid == 0) {
    Z[r] = M + logf(sred[4] + sred[5] + sred[6] + sred[7]);
  }
}

// ---------------------------------------------------------------------------
// K2: C[h] = 0.25 * sum_s Z[s*H + h]
// ---------------------------------------------------------------------------
__global__ __launch_bounds__(512) void k_cvec(const float* __restrict__ Z,
                                              float* __restrict__ C) {
  const int h = threadIdx.x;
  C[h] = 0.25f * (Z[h] + Z[Hq + h] + Z[2 * Hq + h] + Z[3 * Hq + h]);
}

// ---------------------------------------------------------------------------
// K3: E8[j,k] = fp8_e4m3( 1024 * softmax_k(tran[j,:]) )   (packed 4/word)
// ---------------------------------------------------------------------------
__global__ __launch_bounds__(512) void k_tran_softmax(const float* __restrict__ tr,
                                                      unsigned int* __restrict__ E8w) {
  const int j = blockIdx.x, tid = threadIdx.x;
  const int lane = tid & 63, wid = tid >> 6;
  __shared__ float sred[16];
  __shared__ float p[Hq];
  const float t = tr[j * Hq + tid];
  float m = t;
#pragma unroll
  for (int o = 32; o; o >>= 1) m = fmaxf(m, __shfl_xor(m, o));
  if (lane == 0) sred[wid] = m;
  __syncthreads();
  float M = sred[0];
#pragma unroll
  for (int q = 1; q < 8; ++q) M = fmaxf(M, sred[q]);
  const float e = expf(t - M);
  float s = e;
#pragma unroll
  for (int o = 32; o; o >>= 1) s += __shfl_xor(s, o);
  if (lane == 0) sred[8 + wid] = s;
  __syncthreads();
  float S = 0.f;
#pragma unroll
  for (int q = 0; q < 8; ++q) S += sred[8 + q];
  p[tid] = 1024.0f * e / S;
  __syncthreads();
  if (tid < 128) {
    int w0 = __builtin_amdgcn_cvt_pk_fp8_f32(p[4 * tid], p[4 * tid + 1], 0, false);
    w0 = __builtin_amdgcn_cvt_pk_fp8_f32(p[4 * tid + 2], p[4 * tid + 3], w0, true);
    E8w[j * 128 + tid] = (unsigned int)w0;
  }
}

// ---------------------------------------------------------------------------
// K4: transpose U (S,H,V) -> UT (S,V,H) so per-(s,v) h-vectors are contiguous
// ---------------------------------------------------------------------------
__global__ __launch_bounds__(256) void k_transpose(const float* __restrict__ U,
                                                   float* __restrict__ UT) {
  __shared__ float tile[32][33];
  const int s = blockIdx.z;
  const int v0 = blockIdx.x * 32, h0 = blockIdx.y * 32;
  const int tx = threadIdx.x, ty = threadIdx.y;  // 32 x 8
#pragma unroll
  for (int q = 0; q < 4; ++q) {
    const int h = h0 + ty + q * 8;
    const int v = v0 + tx;
    if (v < Vq) tile[ty + q * 8][tx] = U[((size_t)s * Hq + h) * Vq + v];
  }
  __syncthreads();
#pragma unroll
  for (int q = 0; q < 4; ++q) {
    const int v = v0 + ty + q * 8;
    if (v < Vq) UT[((size_t)s * Vq + v) * Hq + h0 + tx] = tile[tx][ty + q * 8];
  }
}

// ---------------------------------------------------------------------------
// Emission for one (b,t), state k:  0.25*sum_s table[s][obs_s][k] - C[k]
// ---------------------------------------------------------------------------
__device__ __forceinline__ float emis_at(const float* __restrict__ U,
                                         const float* __restrict__ UT,
                                         const float* __restrict__ C,
                                         const int* __restrict__ ob, int k,
                                         int use_ut) {
  float e;
  if (use_ut) {
    e = UT[((size_t)0 * Vq + ob[0]) * Hq + k] +
        UT[((size_t)1 * Vq + ob[1]) * Hq + k] +
        UT[((size_t)2 * Vq + ob[2]) * Hq + k] +
        UT[((size_t)3 * Vq + ob[3]) * Hq + k];
  } else {
    e = U[((size_t)0 * Hq + k) * Vq + ob[0]] +
        U[((size_t)1 * Hq + k) * Vq + ob[1]] +
        U[((size_t)2 * Hq + k) * Vq + ob[2]] +
        U[((size_t)3 * Hq + k) * Vq + ob[3]];
  }
  return 0.25f * e - C[k];
}

// ---------------------------------------------------------------------------
// K5: forward recursion. One workgroup per batch element b; 512 threads.
// R1-R3: matvec bound by E load-instruction count. R4: reg-resident E was
// right but the compiler capped VGPRs at 128 (no waves-per-EU hint) and
// spilled er[] to scratch (WRITE_SIZE 42 GB, 6x regression).
// Fix: __launch_bounds__(512, 2) -> 2 waves/EU -> VGPR cap 256. Demand:
// er[32] uint4 = 128 (E slice) + acc[16] + ~30 scalars ~= 180 < 256.
// Per step the matvec is pure VALU+LDS, zero global loads:
//   thread (g = tid>>5, i = tid&31) owns j in [32g,32g+32), k in [16i,16i+16)
//   B1: publish per-wave max of alpha -> M
//   B2: publish w_j = exp(alpha_j - M)
//   32-iter unrolled: wj = w[32g+jj] (LDS broadcast), 8 cvt_pk_f32_fp8 +
//   16 v_fmac into acc[16]
//   B3: publish partials part2[g][q][i]; alpha_k = em + M + log(sum) - ln1024
// Early-exits at t = lengths[b]-1, then out[b] = logsumexp_k alpha.
// ---------------------------------------------------------------------------
__global__ __launch_bounds__(512, 2) void k_forward(
    const int* __restrict__ obs, const int* __restrict__ lengths,
    const float* __restrict__ U, const float* __restrict__ UT,
    const float* __restrict__ C, const unsigned int* __restrict__ E8,
    const float* __restrict__ pri, float* __restrict__ out, int use_ut) {
  const int b = blockIdx.x;
  const int tid = threadIdx.x;           // = state k it owns for alpha
  const int lane = tid & 63, wid = tid >> 6;
  const int L = lengths[b];

  __shared__ float w[Hq];                // 2 KB
  __shared__ float4 part2[16][4][33];    // [g][q][i], i-padded: 33.8 KB
  __shared__ float red[16];

  const int g = tid >> 5;   // j-group 0..15 (each covers 32 j)
  const int i = tid & 31;   // k-16-tuple: k = 16*i .. 16*i+15

  // Preload this thread's E slice into registers: rows 32g..32g+31,
  // 16 fp8 per row starting at k=16i. uint4 = 16 fp8.
  const uint4* E8v4 = (const uint4*)E8;  // row j = 32 uint4
  uint4 er[32];
#pragma unroll
  for (int jj = 0; jj < 32; ++jj) {
    er[jj] = E8v4[(size_t)(32 * g + jj) * 32 + i];
  }

  // invariant decomposition for the final partial-sum read: k = tid
  const int ip = tid >> 4, qq = (tid >> 2) & 3, rr = tid & 3;

  // t = 0
  const int* ob0 = obs + ((size_t)b * Tq + 0) * Sq;
  float a = emis_at(U, UT, C, ob0, tid, use_ut) + pri[tid];

  for (int t = 1; t < L; ++t) {
    // issue emission gathers early (independent of the reduce/matvec)
    const int* obt = obs + ((size_t)b * Tq + t) * Sq;
    const float emt = emis_at(U, UT, C, obt, tid, use_ut);

    // block max of alpha
    float m = a;
#pragma unroll
    for (int o = 32; o; o >>= 1) m = fmaxf(m, __shfl_xor(m, o));
    if (lane == 0) red[wid] = m;
    __syncthreads();  // B1: red published; prev-iter part2 reads complete
    float M = red[0];
#pragma unroll
    for (int q = 1; q < 8; ++q) M = fmaxf(M, red[q]);

    w[tid] = expf(a - M);
    __syncthreads();  // B2: w published

    // matvec from registers: k = 16i..16i+15 over j in [32g, 32g+32)
    float acc[16];
#pragma unroll
    for (int q = 0; q < 16; ++q) acc[q] = 0.f;
    const float* wg = &w[32 * g];
#pragma unroll
    for (int jj = 0; jj < 32; ++jj) {
      const float wj = wg[jj];
      const uint4 e = er[jj];
      floatx2 p;
      p = __builtin_amdgcn_cvt_pk_f32_fp8(e.x, false);
      acc[0] += wj * p.x;  acc[1] += wj * p.y;
      p = __builtin_amdgcn_cvt_pk_f32_fp8(e.x, true);
      acc[2] += wj * p.x;  acc[3] += wj * p.y;
      p = __builtin_amdgcn_cvt_pk_f32_fp8(e.y, false);
      acc[4] += wj * p.x;  acc[5] += wj * p.y;
      p = __builtin_amdgcn_cvt_pk_f32_fp8(e.y, true);
      acc[6] += wj * p.x;  acc[7] += wj * p.y;
      p = __builtin_amdgcn_cvt_pk_f32_fp8(e.z, false);
      acc[8] += wj * p.x;  acc[9] += wj * p.y;
      p = __builtin_amdgcn_cvt_pk_f32_fp8(e.z, true);
      acc[10] += wj * p.x; acc[11] += wj * p.y;
      p = __builtin_amdgcn_cvt_pk_f32_fp8(e.w, false);
      acc[12] += wj * p.x; acc[13] += wj * p.y;
      p = __builtin_amdgcn_cvt_pk_f32_fp8(e.w, true);
      acc[14] += wj * p.x; acc[15] += wj * p.y;
    }
#pragma unroll
    for (int q = 0; q < 4; ++q) {
      part2[g][q][i] = float4{acc[4 * q], acc[4 * q + 1], acc[4 * q + 2],
                              acc[4 * q + 3]};
    }
    __syncthreads();  // B3: part2 published; w reads complete

    // ssum over the 16 j-groups for k = tid = 16*ip + 4*qq + rr
    float ssum = 0.f;
#pragma unroll
    for (int gg = 0; gg < 16; ++gg) {
      const float* p4 = (const float*)&part2[gg][qq][ip];
      ssum += p4[rr];
    }
    a = emt + M + logf(ssum) - LOG_E_SCALE;
    // part2 reads above happen-before next B1 -> next part2 write (post-B2)
  }

  // out[b] = logsumexp_k a
  float m = a;
#pragma unroll
  for (int o = 32; o; o >>= 1) m = fmaxf(m, __shfl_xor(m, o));
  if (lane == 0) red[wid] = m;
  __syncthreads();
  float M = red[0];
#pragma unroll
  for (int q = 1; q < 8; ++q) M = fmaxf(M, red[q]);
  float e = expf(a - M);
#pragma unroll
  for (int o = 32; o; o >>= 1) e += __shfl_xor(e, o);
  if (lane == 0) red[8 + wid] = e;
  __syncthreads();
  if (tid == 0) {
    float S = 0.f;
#pragma unroll
    for (int q = 0; q < 8; ++q) S += red[8 + q];
    out[b] = M + logf(S);
  }
}

// ---------------------------------------------------------------------------
// Workspace layout (bytes):
//   E8  : [0, 262144)                 fp8 1024*softmax(tran)  256 KB
//   Z   : [262144, 270336)            per-(s,h) row LSE       8 KB
//   C   : [270336, 272384)            emission constant       2 KB
//   UT  : [272384, 272384+81920000)   transposed table        81.9 MB
// ---------------------------------------------------------------------------
extern "C" void kernel_launch(void* const* d_in, const int* in_sizes, int n_in,
                              void* d_out, int out_size, void* d_ws,
                              size_t ws_size, hipStream_t stream) {
  const int* obs = (const int*)d_in[0];
  const int* lengths = (const int*)d_in[1];
  const float* U = (const float*)d_in[2];       // unnormalized_emis (S,H,V)
  const float* tran = (const float*)d_in[3];    // unnormalized_tran (H,H)
  const float* pri = (const float*)d_in[4];     // log_state_priors (H,)
  float* out = (float*)d_out;

  char* ws = (char*)d_ws;
  unsigned int* E8 = (unsigned int*)ws;
  float* Z = (float*)(ws + 262144);
  float* C = (float*)(ws + 270336);
  float* UT = (float*)(ws + 272384);

  const size_t need_ut_bytes = 272384ull + 81920000ull;
  const int use_ut = (ws_size >= need_ut_bytes) ? 1 : 0;

  k_row_lse<<<Sq * Hq, 256, 0, stream>>>(U, Z);
  k_cvec<<<1, 512, 0, stream>>>(Z, C);
  k_tran_softmax<<<Hq, 512, 0, stream>>>(tran, E8);
  if (use_ut) {
    dim3 grid((Vq + 31) / 32, Hq / 32, Sq);
    k_transpose<<<grid, dim3(32, 8), 0, stream>>>(U, UT);
  }
  k_forward<<<Bq, 512, 0, stream>>>(obs, lengths, U, UT, C, E8, pri, out,
                                    use_ut);
}

// Round 7
// 11431.555 us; speedup vs baseline: 1.3000x; 1.1942x over previous
//
#include <hip/hip_runtime.h>
#include <hip/hip_fp16.h>
#include <cstdint>
#include <cstddef>

// Problem constants (match reference)
#define Bq 64
#define Tq 512
#define Sq 4
#define Hq 512
#define Vq 10000

typedef float floatx2 __attribute__((ext_vector_type(2)));

// ln(1024): E is stored as fp8 of (1024 * softmax(tran)) so entries land in
// e4m3's normal range [0.037, 40] (unscaled they'd sit at the subnormal
// granularity 2^-9 and quantize catastrophically).
#define LOG_E_SCALE 6.931471805599453f

// ---------------------------------------------------------------------------
// K1: Z[r] = logsumexp_v U[r, :]  for r in [0, S*H)   (rows of length V)
// ---------------------------------------------------------------------------
__global__ __launch_bounds__(256) void k_row_lse(const float* __restrict__ U,
                                                 float* __restrict__ Z) {
  const int r = blockIdx.x;
  const int tid = threadIdx.x;
  const int lane = tid & 63, wid = tid >> 6;
  __shared__ float sred[8];
  const float4* row = (const float4*)(U + (size_t)r * Vq);  // V=10000 -> 2500 float4
  float m = -1e30f;
  for (int i = tid; i < Vq / 4; i += 256) {
    float4 x = row[i];
    m = fmaxf(fmaxf(m, fmaxf(x.x, x.y)), fmaxf(x.z, x.w));
  }
#pragma unroll
  for (int o = 32; o; o >>= 1) m = fmaxf(m, __shfl_xor(m, o));
  if (lane == 0) sred[wid] = m;
  __syncthreads();
  const float M = fmaxf(fmaxf(sred[0], sred[1]), fmaxf(sred[2], sred[3]));
  float s = 0.f;
  for (int i = tid; i < Vq / 4; i += 256) {
    float4 x = row[i];
    s += expf(x.x - M) + expf(x.y - M) + expf(x.z - M) + expf(x.w - M);
  }
#pragma unroll
  for (int o = 32; o; o >>= 1) s += __shfl_xor(s, o);
  if (lane == 0) sred[4 + wid] = s;
  __syncthreads();
  if (tid == 0) {
    Z[r] = M + logf(sred[4] + sred[5] + sred[6] + sred[7]);
  }
}

// ---------------------------------------------------------------------------
// K2: C[h] = 0.25 * sum_s Z[s*H + h]
// ---------------------------------------------------------------------------
__global__ __launch_bounds__(512) void k_cvec(const float* __restrict__ Z,
                                              float* __restrict__ C) {
  const int h = threadIdx.x;
  C[h] = 0.25f * (Z[h] + Z[Hq + h] + Z[2 * Hq + h] + Z[3 * Hq + h]);
}

// ---------------------------------------------------------------------------
// K3: E8[j,k] = fp8_e4m3( 1024 * softmax_k(tran[j,:]) )   (packed 4/word)
// ---------------------------------------------------------------------------
__global__ __launch_bounds__(512) void k_tran_softmax(const float* __restrict__ tr,
                                                      unsigned int* __restrict__ E8w) {
  const int j = blockIdx.x, tid = threadIdx.x;
  const int lane = tid & 63, wid = tid >> 6;
  __shared__ float sred[16];
  __shared__ float p[Hq];
  const float t = tr[j * Hq + tid];
  float m = t;
#pragma unroll
  for (int o = 32; o; o >>= 1) m = fmaxf(m, __shfl_xor(m, o));
  if (lane == 0) sred[wid] = m;
  __syncthreads();
  float M = sred[0];
#pragma unroll
  for (int q = 1; q < 8; ++q) M = fmaxf(M, sred[q]);
  const float e = expf(t - M);
  float s = e;
#pragma unroll
  for (int o = 32; o; o >>= 1) s += __shfl_xor(s, o);
  if (lane == 0) sred[8 + wid] = s;
  __syncthreads();
  float S = 0.f;
#pragma unroll
  for (int q = 0; q < 8; ++q) S += sred[8 + q];
  p[tid] = 1024.0f * e / S;
  __syncthreads();
  if (tid < 128) {
    int w0 = __builtin_amdgcn_cvt_pk_fp8_f32(p[4 * tid], p[4 * tid + 1], 0, false);
    w0 = __builtin_amdgcn_cvt_pk_fp8_f32(p[4 * tid + 2], p[4 * tid + 3], w0, true);
    E8w[j * 128 + tid] = (unsigned int)w0;
  }
}

// ---------------------------------------------------------------------------
// K4: transpose U (S,H,V) -> UT (S,V,H) so per-(s,v) h-vectors are contiguous
// ---------------------------------------------------------------------------
__global__ __launch_bounds__(256) void k_transpose(const float* __restrict__ U,
                                                   float* __restrict__ UT) {
  __shared__ float tile[32][33];
  const int s = blockIdx.z;
  const int v0 = blockIdx.x * 32, h0 = blockIdx.y * 32;
  const int tx = threadIdx.x, ty = threadIdx.y;  // 32 x 8
#pragma unroll
  for (int q = 0; q < 4; ++q) {
    const int h = h0 + ty + q * 8;
    const int v = v0 + tx;
    if (v < Vq) tile[ty + q * 8][tx] = U[((size_t)s * Hq + h) * Vq + v];
  }
  __syncthreads();
#pragma unroll
  for (int q = 0; q < 4; ++q) {
    const int v = v0 + ty + q * 8;
    if (v < Vq) UT[((size_t)s * Vq + v) * Hq + h0 + tx] = tile[tx][ty + q * 8];
  }
}

// ---------------------------------------------------------------------------
// Emission for one (b,t), state k:  0.25*sum_s table[s][obs_s][k] - C[k]
// ---------------------------------------------------------------------------
__device__ __forceinline__ float emis_at(const float* __restrict__ U,
                                         const float* __restrict__ UT,
                                         const float* __restrict__ C,
                                         const int* __restrict__ ob, int k,
                                         int use_ut) {
  float e;
  if (use_ut) {
    e = UT[((size_t)0 * Vq + ob[0]) * Hq + k] +
        UT[((size_t)1 * Vq + ob[1]) * Hq + k] +
        UT[((size_t)2 * Vq + ob[2]) * Hq + k] +
        UT[((size_t)3 * Vq + ob[3]) * Hq + k];
  } else {
    e = U[((size_t)0 * Hq + k) * Vq + ob[0]] +
        U[((size_t)1 * Hq + k) * Vq + ob[1]] +
        U[((size_t)2 * Hq + k) * Vq + ob[2]] +
        U[((size_t)3 * Hq + k) * Vq + ob[3]];
  }
  return 0.25f * e - C[k];
}

// ---------------------------------------------------------------------------
// K5: forward recursion. One workgroup per batch element b; 1024 threads.
// History: R1-R3 matvec bound by E load count -> make E register-resident.
// R4/R6: at 512 thr the E slice is 128 VGPR but the allocator pins the cap
// at 128 (launch_bounds 2nd arg did NOT raise it) and thrashes acc/er via
// scratch (WRITE_SIZE 42 GB). Fix here: 1024 threads halves the per-thread
// E slice to 64 VGPR (32 x uint2); total demand ~100 < 128 cap. Occupancy
// pinned to exactly 1 WG/CU (16 waves) via amdgpu_waves_per_eu(4,4) so the
// scheduler cannot target 8 waves/SIMD (64-VGPR cap) and re-spill.
// Thread (g = tid>>6, i = tid&63): j in [32g,32g+32), k in [8i,8i+8).
// One wave == one j-group -> w[j] reads are LDS broadcasts.
// Per step (3 barriers):
//   B1: waves 0-7 publish per-wave max of alpha -> M
//   B2: tid<512 publish w_j = exp(alpha_j - M)
//   matvec (all 1024): 32 iters x (4 cvt_pk_f32_fp8 + 8 v_fmac), acc[8]
//   B3: publish part[16][512]; tid<512: alpha_k = em + M + log(sum) - ln1024
// Early-exit at t = lengths[b]-1, then out[b] = logsumexp_k alpha.
// ---------------------------------------------------------------------------
__global__ __launch_bounds__(1024)
__attribute__((amdgpu_waves_per_eu(4, 4)))
void k_forward(
    const int* __restrict__ obs, const int* __restrict__ lengths,
    const float* __restrict__ U, const float* __restrict__ UT,
    const float* __restrict__ C, const unsigned int* __restrict__ E8,
    const float* __restrict__ pri, float* __restrict__ out, int use_ut) {
  const int b = blockIdx.x;
  const int tid = threadIdx.x;
  const int lane = tid & 63, wid = tid >> 6;
  const int L = lengths[b];

  __shared__ float w[Hq];            // 2 KB
  __shared__ float part[16][Hq];     // 32 KB
  __shared__ float red[16];

  const int g = tid >> 6;   // j-group 0..15 (32 j each); == wave id
  const int i = tid & 63;   // k-octet: k = 8i .. 8i+7

  // Preload this thread's E slice: rows 32g..32g+31, 8 fp8 per row at k=8i.
  const uint2* E8v2 = (const uint2*)E8;  // row j = 64 uint2
  uint2 er[32];
#pragma unroll
  for (int jj = 0; jj < 32; ++jj) {
    er[jj] = E8v2[(size_t)(32 * g + jj) * 64 + i];
  }

  // t = 0 (alpha owned by tid<512, k = tid)
  float a = 0.f;
  if (tid < Hq) {
    const int* ob0 = obs + ((size_t)b * Tq + 0) * Sq;
    a = emis_at(U, UT, C, ob0, tid, use_ut) + pri[tid];
  }

  for (int t = 1; t < L; ++t) {
    // issue emission gathers early (independent of the reduce/matvec)
    float emt = 0.f;
    if (tid < Hq) {
      const int* obt = obs + ((size_t)b * Tq + t) * Sq;
      emt = emis_at(U, UT, C, obt, tid, use_ut);
    }

    // block max of alpha over waves 0..7 (wave-uniform branch)
    if (tid < Hq) {
      float m = a;
#pragma unroll
      for (int o = 32; o; o >>= 1) m = fmaxf(m, __shfl_xor(m, o));
      if (lane == 0) red[wid] = m;
    }
    __syncthreads();  // B1: red published; prev-iter part reads complete
    float M = red[0];
#pragma unroll
    for (int q = 1; q < 8; ++q) M = fmaxf(M, red[q]);

    if (tid < Hq) w[tid] = expf(a - M);
    __syncthreads();  // B2: w published

    // matvec from registers: k = 8i..8i+7 over j in [32g, 32g+32)
    float acc[8];
#pragma unroll
    for (int q = 0; q < 8; ++q) acc[q] = 0.f;
    const float* wg = &w[32 * g];
#pragma unroll
    for (int jj = 0; jj < 32; ++jj) {
      const float wj = wg[jj];     // LDS broadcast (whole wave same addr)
      const uint2 e = er[jj];
      floatx2 p;
      p = __builtin_amdgcn_cvt_pk_f32_fp8(e.x, false);
      acc[0] += wj * p.x;  acc[1] += wj * p.y;
      p = __builtin_amdgcn_cvt_pk_f32_fp8(e.x, true);
      acc[2] += wj * p.x;  acc[3] += wj * p.y;
      p = __builtin_amdgcn_cvt_pk_f32_fp8(e.y, false);
      acc[4] += wj * p.x;  acc[5] += wj * p.y;
      p = __builtin_amdgcn_cvt_pk_f32_fp8(e.y, true);
      acc[6] += wj * p.x;  acc[7] += wj * p.y;
    }
    *(float4*)&part[g][8 * i] = float4{acc[0], acc[1], acc[2], acc[3]};
    *(float4*)&part[g][8 * i + 4] = float4{acc[4], acc[5], acc[6], acc[7]};
    __syncthreads();  // B3: part published; w reads complete

    if (tid < Hq) {
      float ssum = 0.f;
#pragma unroll
      for (int gg = 0; gg < 16; ++gg) ssum += part[gg][tid];
      a = emt + M + logf(ssum) - LOG_E_SCALE;
    }
    // part reads above happen-before next B1 -> next part write (post-B2)
  }

  // out[b] = logsumexp_{k<512} a
  if (tid < Hq) {
    float m = a;
#pragma unroll
    for (int o = 32; o; o >>= 1) m = fmaxf(m, __shfl_xor(m, o));
    if (lane == 0) red[wid] = m;
  }
  __syncthreads();
  float M = red[0];
#pragma unroll
  for (int q = 1; q < 8; ++q) M = fmaxf(M, red[q]);
  if (tid < Hq) {
    float e = expf(a - M);
#pragma unroll
    for (int o = 32; o; o >>= 1) e += __shfl_xor(e, o);
    if (lane == 0) red[8 + wid] = e;
  }
  __syncthreads();
  if (tid == 0) {
    float S = 0.f;
#pragma unroll
    for (int q = 0; q < 8; ++q) S += red[8 + q];
    out[b] = M + logf(S);
  }
}

// ---------------------------------------------------------------------------
// Workspace layout (bytes):
//   E8  : [0, 262144)                 fp8 1024*softmax(tran)  256 KB
//   Z   : [262144, 270336)            per-(s,h) row LSE       8 KB
//   C   : [270336, 272384)            emission constant       2 KB
//   UT  : [272384, 272384+81920000)   transposed table        81.9 MB
// ---------------------------------------------------------------------------
extern "C" void kernel_launch(void* const* d_in, const int* in_sizes, int n_in,
                              void* d_out, int out_size, void* d_ws,
                              size_t ws_size, hipStream_t stream) {
  const int* obs = (const int*)d_in[0];
  const int* lengths = (const int*)d_in[1];
  const float* U = (const float*)d_in[2];       // unnormalized_emis (S,H,V)
  const float* tran = (const float*)d_in[3];    // unnormalized_tran (H,H)
  const float* pri = (const float*)d_in[4];     // log_state_priors (H,)
  float* out = (float*)d_out;

  char* ws = (char*)d_ws;
  unsigned int* E8 = (unsigned int*)ws;
  float* Z = (float*)(ws + 262144);
  float* C = (float*)(ws + 270336);
  float* UT = (float*)(ws + 272384);

  const size_t need_ut_bytes = 272384ull + 81920000ull;
  const int use_ut = (ws_size >= need_ut_bytes) ? 1 : 0;

  k_row_lse<<<Sq * Hq, 256, 0, stream>>>(U, Z);
  k_cvec<<<1, 512, 0, stream>>>(Z, C);
  k_tran_softmax<<<Hq, 512, 0, stream>>>(tran, E8);
  if (use_ut) {
    dim3 grid((Vq + 31) / 32, Hq / 32, Sq);
    k_transpose<<<grid, dim3(32, 8), 0, stream>>>(U, UT);
  }
  k_forward<<<Bq, 1024, 0, stream>>>(obs, lengths, U, UT, C, E8, pri, out,
                                     use_ut);
}

// Round 10
// 2508.571 us; speedup vs baseline: 5.9243x; 4.5570x over previous
//
#include <hip/hip_runtime.h>
#include <hip/hip_fp16.h>
#include <cstdint>
#include <cstddef>

// Problem constants (match reference)
#define Bq 64
#define Tq 512
#define Sq 4
#define Hq 512
#define Vq 10000

typedef float floatx2 __attribute__((ext_vector_type(2)));

// ln(1024): E is stored as fp8 of (1024 * softmax(tran)) so entries land in
// e4m3's normal range [0.037, 40].
#define LOG_E_SCALE 6.931471805599453f

// ---------------------------------------------------------------------------
// K1: Z[r] = logsumexp_v U[r, :]  for r in [0, S*H)   (rows of length V)
// ---------------------------------------------------------------------------
__global__ __launch_bounds__(256) void k_row_lse(const float* __restrict__ U,
                                                 float* __restrict__ Z) {
  const int r = blockIdx.x;
  const int tid = threadIdx.x;
  const int lane = tid & 63, wid = tid >> 6;
  __shared__ float sred[8];
  const float4* row = (const float4*)(U + (size_t)r * Vq);
  float m = -1e30f;
  for (int i = tid; i < Vq / 4; i += 256) {
    float4 x = row[i];
    m = fmaxf(fmaxf(m, fmaxf(x.x, x.y)), fmaxf(x.z, x.w));
  }
#pragma unroll
  for (int o = 32; o; o >>= 1) m = fmaxf(m, __shfl_xor(m, o));
  if (lane == 0) sred[wid] = m;
  __syncthreads();
  const float M = fmaxf(fmaxf(sred[0], sred[1]), fmaxf(sred[2], sred[3]));
  float s = 0.f;
  for (int i = tid; i < Vq / 4; i += 256) {
    float4 x = row[i];
    s += expf(x.x - M) + expf(x.y - M) + expf(x.z - M) + expf(x.w - M);
  }
#pragma unroll
  for (int o = 32; o; o >>= 1) s += __shfl_xor(s, o);
  if (lane == 0) sred[4 + wid] = s;
  __syncthreads();
  if (tid == 0) {
    Z[r] = M + logf(sred[4] + sred[5] + sred[6] + sred[7]);
  }
}

// ---------------------------------------------------------------------------
// K2: C[h] = 0.25 * sum_s Z[s*H + h]
// ---------------------------------------------------------------------------
__global__ __launch_bounds__(512) void k_cvec(const float* __restrict__ Z,
                                              float* __restrict__ C) {
  const int h = threadIdx.x;
  C[h] = 0.25f * (Z[h] + Z[Hq + h] + Z[2 * Hq + h] + Z[3 * Hq + h]);
}

// ---------------------------------------------------------------------------
// K3: E8[j,k] = fp8_e4m3( 1024 * softmax_k(tran[j,:]) )   (packed 4/word)
// ---------------------------------------------------------------------------
__global__ __launch_bounds__(512) void k_tran_softmax(const float* __restrict__ tr,
                                                      unsigned int* __restrict__ E8w) {
  const int j = blockIdx.x, tid = threadIdx.x;
  const int lane = tid & 63, wid = tid >> 6;
  __shared__ float sred[16];
  __shared__ float p[Hq];
  const float t = tr[j * Hq + tid];
  float m = t;
#pragma unroll
  for (int o = 32; o; o >>= 1) m = fmaxf(m, __shfl_xor(m, o));
  if (lane == 0) sred[wid] = m;
  __syncthreads();
  float M = sred[0];
#pragma unroll
  for (int q = 1; q < 8; ++q) M = fmaxf(M, sred[q]);
  const float e = expf(t - M);
  float s = e;
#pragma unroll
  for (int o = 32; o; o >>= 1) s += __shfl_xor(s, o);
  if (lane == 0) sred[8 + wid] = s;
  __syncthreads();
  float S = 0.f;
#pragma unroll
  for (int q = 0; q < 8; ++q) S += sred[8 + q];
  p[tid] = 1024.0f * e / S;
  __syncthreads();
  if (tid < 128) {
    int w0 = __builtin_amdgcn_cvt_pk_fp8_f32(p[4 * tid], p[4 * tid + 1], 0, false);
    w0 = __builtin_amdgcn_cvt_pk_fp8_f32(p[4 * tid + 2], p[4 * tid + 3], w0, true);
    E8w[j * 128 + tid] = (unsigned int)w0;
  }
}

// ---------------------------------------------------------------------------
// K4: transpose U (S,H,V) -> UT (S,V,H) so per-(s,v) h-vectors are contiguous
// ---------------------------------------------------------------------------
__global__ __launch_bounds__(256) void k_transpose(const float* __restrict__ U,
                                                   float* __restrict__ UT) {
  __shared__ float tile[32][33];
  const int s = blockIdx.z;
  const int v0 = blockIdx.x * 32, h0 = blockIdx.y * 32;
  const int tx = threadIdx.x, ty = threadIdx.y;  // 32 x 8
#pragma unroll
  for (int q = 0; q < 4; ++q) {
    const int h = h0 + ty + q * 8;
    const int v = v0 + tx;
    if (v < Vq) tile[ty + q * 8][tx] = U[((size_t)s * Hq + h) * Vq + v];
  }
  __syncthreads();
#pragma unroll
  for (int q = 0; q < 4; ++q) {
    const int v = v0 + ty + q * 8;
    if (v < Vq) UT[((size_t)s * Vq + v) * Hq + h0 + tx] = tile[tx][ty + q * 8];
  }
}

// ---------------------------------------------------------------------------
// Emission for one (b,t), state k:  0.25*sum_s table[s][obs_s][k] - C[k]
// ---------------------------------------------------------------------------
__device__ __forceinline__ float emis_at(const float* __restrict__ U,
                                         const float* __restrict__ UT,
                                         const float* __restrict__ C,
                                         const int* __restrict__ ob, int k,
                                         int use_ut) {
  float e;
  if (use_ut) {
    e = UT[((size_t)0 * Vq + ob[0]) * Hq + k] +
        UT[((size_t)1 * Vq + ob[1]) * Hq + k] +
        UT[((size_t)2 * Vq + ob[2]) * Hq + k] +
        UT[((size_t)3 * Vq + ob[3]) * Hq + k];
  } else {
    e = U[((size_t)0 * Hq + k) * Vq + ob[0]] +
        U[((size_t)1 * Hq + k) * Vq + ob[1]] +
        U[((size_t)2 * Hq + k) * Vq + ob[2]] +
        U[((size_t)3 * Hq + k) * Vq + ob[3]];
  }
  return 0.25f * e - C[k];
}

// ---------------------------------------------------------------------------
// K5: forward recursion. One WG per chain b; 512 threads (8 waves).
// History: R1-R3 = E-stream latency-bound (23 B/cyc eff). R4/R6/R7 =
// register-resident E always spilled (allocator caps VGPR at 64-128 no
// matter the hints; WRITE_SIZE 42-47 GB). Lesson: the only on-CU store we
// control is LDS. This round: E tiles staged in LDS, double-buffered,
// loads for tile p+1 issued before compute of tile p (T14 async-stage) so
// the L2 stream runs at BW not latency. Tiles 0,1 (rows 0..127, 64 KB)
// are PINNED in LDS across all steps (E is step-invariant) -> only 192 KB
// streamed/step. 149.5 KB LDS also forces 1 WG/CU (VGPR cap 256, no spill).
// Decomposition per tile (64 j-rows): wave g (0..7) handles rows 8g..8g+8;
// lane i covers k = 8i..8i+7 (uint2 = 8 fp8 LDS reads); acc[8] carried
// across all 8 tiles; part[8][512] + one barrier combines the 8 waves.
// Per step: B1 (max) B2 (w) | resident t0, ds_write s0, resident t1, bar |
// 6 streamed tiles (load s+1 -> regs; compute s; ds_write s+1; bar) | ssum.
// ---------------------------------------------------------------------------
__global__ __launch_bounds__(512) void k_forward(
    const int* __restrict__ obs, const int* __restrict__ lengths,
    const float* __restrict__ U, const float* __restrict__ UT,
    const float* __restrict__ C, const unsigned int* __restrict__ E8,
    const float* __restrict__ pri, float* __restrict__ out, int use_ut) {
  const int b = blockIdx.x;
  const int tid = threadIdx.x;
  const int lane = tid & 63, wid = tid >> 6;
  const int L = lengths[b];

  // 4 slots x 32 KB: slots 0,1 = pinned tiles 0,1; slots 2,3 = stream dbuf
  __shared__ uint4 elds4[4 * 2048];   // 128 KB
  __shared__ float w[Hq];             // 2 KB
  __shared__ float part[8][Hq];       // 16 KB
  __shared__ float red[16];

  const int g = tid >> 6;   // wave id = j-chunk 0..7 (8 rows per tile)
  const int i = tid & 63;   // k-octet: k = 8i..8i+7

  const uint4* Eg4 = (const uint4*)E8;  // tile tau: Eg4[tau*2048 + q*512 + t]

  // ---- prologue: pin tiles 0,1 (rows 0..127) into slots 0,1 ----
  {
    uint4 a0 = Eg4[0 * 512 + tid], a1 = Eg4[1 * 512 + tid];
    uint4 a2 = Eg4[2 * 512 + tid], a3 = Eg4[3 * 512 + tid];
    uint4 b0 = Eg4[2048 + 0 * 512 + tid], b1 = Eg4[2048 + 1 * 512 + tid];
    uint4 b2 = Eg4[2048 + 2 * 512 + tid], b3 = Eg4[2048 + 3 * 512 + tid];
    elds4[0 * 512 + tid] = a0; elds4[1 * 512 + tid] = a1;
    elds4[2 * 512 + tid] = a2; elds4[3 * 512 + tid] = a3;
    elds4[2048 + 0 * 512 + tid] = b0; elds4[2048 + 1 * 512 + tid] = b1;
    elds4[2048 + 2 * 512 + tid] = b2; elds4[2048 + 3 * 512 + tid] = b3;
  }

  // t = 0
  const int* ob0 = obs + ((size_t)b * Tq + 0) * Sq;
  float a = emis_at(U, UT, C, ob0, tid, use_ut) + pri[tid];
  __syncthreads();  // pinned tiles visible

  const unsigned char* eb = (const unsigned char*)elds4;

  for (int t = 1; t < L; ++t) {
    // issue stream loads for tile 2 (s=0) + emission gathers early
    uint4 ra0 = Eg4[2 * 2048 + 0 * 512 + tid];
    uint4 ra1 = Eg4[2 * 2048 + 1 * 512 + tid];
    uint4 ra2 = Eg4[2 * 2048 + 2 * 512 + tid];
    uint4 ra3 = Eg4[2 * 2048 + 3 * 512 + tid];
    uint4 rb0, rb1, rb2, rb3;
    const int* obt = obs + ((size_t)b * Tq + t) * Sq;
    const float emt = emis_at(U, UT, C, obt, tid, use_ut);

    // B1: block max of alpha
    float m = a;
#pragma unroll
    for (int o = 32; o; o >>= 1) m = fmaxf(m, __shfl_xor(m, o));
    if (lane == 0) red[wid] = m;
    __syncthreads();
    float M = red[0];
#pragma unroll
    for (int q = 1; q < 8; ++q) M = fmaxf(M, red[q]);

    w[tid] = expf(a - M);
    __syncthreads();  // B2: w published

    float acc[8];
#pragma unroll
    for (int q = 0; q < 8; ++q) acc[q] = 0.f;

    // compute one 64-row tile from LDS slot
#define COMP_TILE(TAU, SLOT)                                              \
    {                                                                     \
      const int jb = (TAU) * 64 + 8 * g;                                  \
      const unsigned char* sl = eb + (size_t)(SLOT) * 32768;              \
      _Pragma("unroll")                                                   \
      for (int jj = 0; jj < 8; ++jj) {                                    \
        const float wj = w[jb + jj];                                      \
        const uint2 e = *(const uint2*)&sl[(8 * g + jj) * 512 + 8 * i];   \
        floatx2 p;                                                        \
        p = __builtin_amdgcn_cvt_pk_f32_fp8(e.x, false);                  \
        acc[0] += wj * p.x;  acc[1] += wj * p.y;                          \
        p = __builtin_amdgcn_cvt_pk_f32_fp8(e.x, true);                   \
        acc[2] += wj * p.x;  acc[3] += wj * p.y;                          \
        p = __builtin_amdgcn_cvt_pk_f32_fp8(e.y, false);                  \
        acc[4] += wj * p.x;  acc[5] += wj * p.y;                          \
        p = __builtin_amdgcn_cvt_pk_f32_fp8(e.y, true);                   \
        acc[6] += wj * p.x;  acc[7] += wj * p.y;                          \
      }                                                                   \
    }

    // resident tiles; meanwhile write s=0 into slot 2 (loads arrive under B1/B2)
    COMP_TILE(0, 0);
    elds4[2 * 2048 + 0 * 512 + tid] = ra0;
    elds4[2 * 2048 + 1 * 512 + tid] = ra1;
    elds4[2 * 2048 + 2 * 512 + tid] = ra2;
    elds4[2 * 2048 + 3 * 512 + tid] = ra3;
    COMP_TILE(1, 1);
    __syncthreads();  // slot 2 ready

    // streamed tiles s=0..5 (tau = s+2, slot = 2+(s&1)), dbuf pipeline
    // s=0: load tile3->rb, compute slot2, write rb->slot3
    rb0 = Eg4[3 * 2048 + 0 * 512 + tid]; rb1 = Eg4[3 * 2048 + 1 * 512 + tid];
    rb2 = Eg4[3 * 2048 + 2 * 512 + tid]; rb3 = Eg4[3 * 2048 + 3 * 512 + tid];
    COMP_TILE(2, 2);
    elds4[3 * 2048 + 0 * 512 + tid] = rb0; elds4[3 * 2048 + 1 * 512 + tid] = rb1;
    elds4[3 * 2048 + 2 * 512 + tid] = rb2; elds4[3 * 2048 + 3 * 512 + tid] = rb3;
    __syncthreads();
    // s=1: load tile4->ra, compute slot3, write ra->slot2
    ra0 = Eg4[4 * 2048 + 0 * 512 + tid]; ra1 = Eg4[4 * 2048 + 1 * 512 + tid];
    ra2 = Eg4[4 * 2048 + 2 * 512 + tid]; ra3 = Eg4[4 * 2048 + 3 * 512 + tid];
    COMP_TILE(3, 3);
    elds4[2 * 2048 + 0 * 512 + tid] = ra0; elds4[2 * 2048 + 1 * 512 + tid] = ra1;
    elds4[2 * 2048 + 2 * 512 + tid] = ra2; elds4[2 * 2048 + 3 * 512 + tid] = ra3;
    __syncthreads();
    // s=2: load tile5->rb, compute slot2, write rb->slot3
    rb0 = Eg4[5 * 2048 + 0 * 512 + tid]; rb1 = Eg4[5 * 2048 + 1 * 512 + tid];
    rb2 = Eg4[5 * 2048 + 2 * 512 + tid]; rb3 = Eg4[5 * 2048 + 3 * 512 + tid];
    COMP_TILE(4, 2);
    elds4[3 * 2048 + 0 * 512 + tid] = rb0; elds4[3 * 2048 + 1 * 512 + tid] = rb1;
    elds4[3 * 2048 + 2 * 512 + tid] = rb2; elds4[3 * 2048 + 3 * 512 + tid] = rb3;
    __syncthreads();
    // s=3: load tile6->ra, compute slot3, write ra->slot2
    ra0 = Eg4[6 * 2048 + 0 * 512 + tid]; ra1 = Eg4[6 * 2048 + 1 * 512 + tid];
    ra2 = Eg4[6 * 2048 + 2 * 512 + tid]; ra3 = Eg4[6 * 2048 + 3 * 512 + tid];
    COMP_TILE(5, 3);
    elds4[2 * 2048 + 0 * 512 + tid] = ra0; elds4[2 * 2048 + 1 * 512 + tid] = ra1;
    elds4[2 * 2048 + 2 * 512 + tid] = ra2; elds4[2 * 2048 + 3 * 512 + tid] = ra3;
    __syncthreads();
    // s=4: load tile7->rb, compute slot2, write rb->slot3
    rb0 = Eg4[7 * 2048 + 0 * 512 + tid]; rb1 = Eg4[7 * 2048 + 1 * 512 + tid];
    rb2 = Eg4[7 * 2048 + 2 * 512 + tid]; rb3 = Eg4[7 * 2048 + 3 * 512 + tid];
    COMP_TILE(6, 2);
    elds4[3 * 2048 + 0 * 512 + tid] = rb0; elds4[3 * 2048 + 1 * 512 + tid] = rb1;
    elds4[3 * 2048 + 2 * 512 + tid] = rb2; elds4[3 * 2048 + 3 * 512 + tid] = rb3;
    __syncthreads();
    // s=5: compute slot3, publish partials
    COMP_TILE(7, 3);
    *(float4*)&part[g][8 * i] = float4{acc[0], acc[1], acc[2], acc[3]};
    *(float4*)&part[g][8 * i + 4] = float4{acc[4], acc[5], acc[6], acc[7]};
    __syncthreads();  // B3

    float ssum = 0.f;
#pragma unroll
    for (int gg = 0; gg < 8; ++gg) ssum += part[gg][tid];
    a = emt + M + logf(ssum) - LOG_E_SCALE;
#undef COMP_TILE
  }

  // out[b] = logsumexp_k a
  float m = a;
#pragma unroll
  for (int o = 32; o; o >>= 1) m = fmaxf(m, __shfl_xor(m, o));
  if (lane == 0) red[wid] = m;
  __syncthreads();
  float M = red[0];
#pragma unroll
  for (int q = 1; q < 8; ++q) M = fmaxf(M, red[q]);
  float e = expf(a - M);
#pragma unroll
  for (int o = 32; o; o >>= 1) e += __shfl_xor(e, o);
  if (lane == 0) red[8 + wid] = e;
  __syncthreads();
  if (tid == 0) {
    float S = 0.f;
#pragma unroll
    for (int q = 0; q < 8; ++q) S += red[8 + q];
    out[b] = M + logf(S);
  }
}

// ---------------------------------------------------------------------------
// Workspace layout (bytes):
//   E8  : [0, 262144)                 fp8 1024*softmax(tran)  256 KB
//   Z   : [262144, 270336)            per-(s,h) row LSE       8 KB
//   C   : [270336, 272384)            emission constant       2 KB
//   UT  : [272384, 272384+81920000)   transposed table        81.9 MB
// ---------------------------------------------------------------------------
extern "C" void kernel_launch(void* const* d_in, const int* in_sizes, int n_in,
                              void* d_out, int out_size, void* d_ws,
                              size_t ws_size, hipStream_t stream) {
  const int* obs = (const int*)d_in[0];
  const int* lengths = (const int*)d_in[1];
  const float* U = (const float*)d_in[2];       // unnormalized_emis (S,H,V)
  const float* tran = (const float*)d_in[3];    // unnormalized_tran (H,H)
  const float* pri = (const float*)d_in[4];     // log_state_priors (H,)
  float* out = (float*)d_out;

  char* ws = (char*)d_ws;
  unsigned int* E8 = (unsigned int*)ws;
  float* Z = (float*)(ws + 262144);
  float* C = (float*)(ws + 270336);
  float* UT = (float*)(ws + 272384);

  const size_t need_ut_bytes = 272384ull + 81920000ull;
  const int use_ut = (ws_size >= need_ut_bytes) ? 1 : 0;

  k_row_lse<<<Sq * Hq, 256, 0, stream>>>(U, Z);
  k_cvec<<<1, 512, 0, stream>>>(Z, C);
  k_tran_softmax<<<Hq, 512, 0, stream>>>(tran, E8);
  if (use_ut) {
    dim3 grid((Vq + 31) / 32, Hq / 32, Sq);
    k_transpose<<<grid, dim3(32, 8), 0, stream>>>(U, UT);
  }
  k_forward<<<Bq, 512, 0, stream>>>(obs, lengths, U, UT, C, E8, pri, out,
                                    use_ut);
}

// Round 11
// 2224.448 us; speedup vs baseline: 6.6810x; 1.1277x over previous
//
#include <hip/hip_runtime.h>
#include <hip/hip_fp16.h>
#include <cstdint>
#include <cstddef>

// Problem constants (match reference)
#define Bq 64
#define Tq 512
#define Sq 4
#define Hq 512
#define Vq 10000

typedef float floatx2 __attribute__((ext_vector_type(2)));

// ln(1024): E is stored as fp8 of (1024 * softmax(tran)) so entries land in
// e4m3's normal range [0.037, 40].
#define LOG_E_SCALE 6.931471805599453f

// ---------------------------------------------------------------------------
// K1: Z[r] = logsumexp_v U[r, :]  for r in [0, S*H)   (rows of length V)
// ---------------------------------------------------------------------------
__global__ __launch_bounds__(256) void k_row_lse(const float* __restrict__ U,
                                                 float* __restrict__ Z) {
  const int r = blockIdx.x;
  const int tid = threadIdx.x;
  const int lane = tid & 63, wid = tid >> 6;
  __shared__ float sred[8];
  const float4* row = (const float4*)(U + (size_t)r * Vq);
  float m = -1e30f;
  for (int i = tid; i < Vq / 4; i += 256) {
    float4 x = row[i];
    m = fmaxf(fmaxf(m, fmaxf(x.x, x.y)), fmaxf(x.z, x.w));
  }
#pragma unroll
  for (int o = 32; o; o >>= 1) m = fmaxf(m, __shfl_xor(m, o));
  if (lane == 0) sred[wid] = m;
  __syncthreads();
  const float M = fmaxf(fmaxf(sred[0], sred[1]), fmaxf(sred[2], sred[3]));
  float s = 0.f;
  for (int i = tid; i < Vq / 4; i += 256) {
    float4 x = row[i];
    s += expf(x.x - M) + expf(x.y - M) + expf(x.z - M) + expf(x.w - M);
  }
#pragma unroll
  for (int o = 32; o; o >>= 1) s += __shfl_xor(s, o);
  if (lane == 0) sred[4 + wid] = s;
  __syncthreads();
  if (tid == 0) {
    Z[r] = M + logf(sred[4] + sred[5] + sred[6] + sred[7]);
  }
}

// ---------------------------------------------------------------------------
// K2: C[h] = 0.25 * sum_s Z[s*H + h]
// ---------------------------------------------------------------------------
__global__ __launch_bounds__(512) void k_cvec(const float* __restrict__ Z,
                                              float* __restrict__ C) {
  const int h = threadIdx.x;
  C[h] = 0.25f * (Z[h] + Z[Hq + h] + Z[2 * Hq + h] + Z[3 * Hq + h]);
}

// ---------------------------------------------------------------------------
// K3: E8[j,k] = fp8_e4m3( 1024 * softmax_k(tran[j,:]) )   (packed 4/word)
// ---------------------------------------------------------------------------
__global__ __launch_bounds__(512) void k_tran_softmax(const float* __restrict__ tr,
                                                      unsigned int* __restrict__ E8w) {
  const int j = blockIdx.x, tid = threadIdx.x;
  const int lane = tid & 63, wid = tid >> 6;
  __shared__ float sred[16];
  __shared__ float p[Hq];
  const float t = tr[j * Hq + tid];
  float m = t;
#pragma unroll
  for (int o = 32; o; o >>= 1) m = fmaxf(m, __shfl_xor(m, o));
  if (lane == 0) sred[wid] = m;
  __syncthreads();
  float M = sred[0];
#pragma unroll
  for (int q = 1; q < 8; ++q) M = fmaxf(M, sred[q]);
  const float e = expf(t - M);
  float s = e;
#pragma unroll
  for (int o = 32; o; o >>= 1) s += __shfl_xor(s, o);
  if (lane == 0) sred[8 + wid] = s;
  __syncthreads();
  float S = 0.f;
#pragma unroll
  for (int q = 0; q < 8; ++q) S += sred[8 + q];
  p[tid] = 1024.0f * e / S;
  __syncthreads();
  if (tid < 128) {
    int w0 = __builtin_amdgcn_cvt_pk_fp8_f32(p[4 * tid], p[4 * tid + 1], 0, false);
    w0 = __builtin_amdgcn_cvt_pk_fp8_f32(p[4 * tid + 2], p[4 * tid + 3], w0, true);
    E8w[j * 128 + tid] = (unsigned int)w0;
  }
}

// ---------------------------------------------------------------------------
// K4: transpose U (S,H,V) -> UT (S,V,H) so per-(s,v) h-vectors are contiguous
// ---------------------------------------------------------------------------
__global__ __launch_bounds__(256) void k_transpose(const float* __restrict__ U,
                                                   float* __restrict__ UT) {
  __shared__ float tile[32][33];
  const int s = blockIdx.z;
  const int v0 = blockIdx.x * 32, h0 = blockIdx.y * 32;
  const int tx = threadIdx.x, ty = threadIdx.y;  // 32 x 8
#pragma unroll
  for (int q = 0; q < 4; ++q) {
    const int h = h0 + ty + q * 8;
    const int v = v0 + tx;
    if (v < Vq) tile[ty + q * 8][tx] = U[((size_t)s * Hq + h) * Vq + v];
  }
  __syncthreads();
#pragma unroll
  for (int q = 0; q < 4; ++q) {
    const int v = v0 + ty + q * 8;
    if (v < Vq) UT[((size_t)s * Vq + v) * Hq + h0 + tx] = tile[tx][ty + q * 8];
  }
}

// ---------------------------------------------------------------------------
// K5: forward recursion. One WG per chain b; 512 threads (8 waves).
// History: R1-R3 stream-shrinking stalled at 4.6us/step; R4/R6/R7 reg-E
// spilled; R8/R10 LDS-dbuf landed at the SAME 4.6us/step with stream bytes,
// barrier count, and staging all varied -> none binding. Diagnosis: every
// version pays a per-step SERIAL latency chain obs(L2)->4x gather(UT,
// L3/HBM ~1-2us) drained by s_waitcnt before B1 (emt summed immediately).
// This round: 2-deep software pipeline of the emission gather. At iter t:
// issue gathers for t+1 (from obn, loaded last iter) + load obs row t+2;
// consume last iter's raw gathers e0..e3 at the alpha update. Each link of
// the chain gets a full step of slack -> latency off the critical path.
// C[tid] and UT base pointers hoisted out of the loop. Rest = R8 structure:
// E fp8 in LDS, tiles 0,1 pinned, tiles 2-7 double-buffered (192 KB/step
// streamed), wave g rows 8g..8g+8/tile, lane i k=8i..8i+7, part[8][512].
// ---------------------------------------------------------------------------
__global__ __launch_bounds__(512) void k_forward(
    const int* __restrict__ obs, const int* __restrict__ lengths,
    const float* __restrict__ U, const float* __restrict__ UT,
    const float* __restrict__ C, const unsigned int* __restrict__ E8,
    const float* __restrict__ pri, float* __restrict__ out, int use_ut) {
  const int b = blockIdx.x;
  const int tid = threadIdx.x;
  const int lane = tid & 63, wid = tid >> 6;
  const int L = lengths[b];

  // 4 slots x 32 KB: slots 0,1 = pinned tiles 0,1; slots 2,3 = stream dbuf
  __shared__ uint4 elds4[4 * 2048];   // 128 KB
  __shared__ float w[Hq];             // 2 KB
  __shared__ float part[8][Hq];       // 16 KB
  __shared__ float red[16];

  const int g = tid >> 6;   // wave id = j-chunk 0..7 (8 rows per tile)
  const int i = tid & 63;   // k-octet: k = 8i..8i+7

  const uint4* Eg4 = (const uint4*)E8;  // tile tau: Eg4[tau*2048 + q*512 + t]

  // ---- prologue: pin tiles 0,1 (rows 0..127) into slots 0,1 ----
  {
    uint4 a0 = Eg4[0 * 512 + tid], a1 = Eg4[1 * 512 + tid];
    uint4 a2 = Eg4[2 * 512 + tid], a3 = Eg4[3 * 512 + tid];
    uint4 b0 = Eg4[2048 + 0 * 512 + tid], b1 = Eg4[2048 + 1 * 512 + tid];
    uint4 b2 = Eg4[2048 + 2 * 512 + tid], b3 = Eg4[2048 + 3 * 512 + tid];
    elds4[0 * 512 + tid] = a0; elds4[1 * 512 + tid] = a1;
    elds4[2 * 512 + tid] = a2; elds4[3 * 512 + tid] = a3;
    elds4[2048 + 0 * 512 + tid] = b0; elds4[2048 + 1 * 512 + tid] = b1;
    elds4[2048 + 2 * 512 + tid] = b2; elds4[2048 + 3 * 512 + tid] = b3;
  }

  // hoisted per-thread emission constants / base pointers
  const float Ck = C[tid];
  const size_t mult = use_ut ? (size_t)Hq : (size_t)1;
  const float* B0 = use_ut ? UT + (size_t)0 * Vq * Hq + tid
                           : U + (size_t)(0 * Hq + tid) * Vq;
  const float* B1p = use_ut ? UT + (size_t)1 * Vq * Hq + tid
                            : U + (size_t)(1 * Hq + tid) * Vq;
  const float* B2p = use_ut ? UT + (size_t)2 * Vq * Hq + tid
                            : U + (size_t)(2 * Hq + tid) * Vq;
  const float* B3p = use_ut ? UT + (size_t)3 * Vq * Hq + tid
                            : U + (size_t)(3 * Hq + tid) * Vq;
  const int4* obs4 = (const int4*)(obs + (size_t)b * Tq * Sq);  // row t

  // t = 0 emission + prior (serial, one-time)
  int4 obc = obs4[0];
  float a = 0.25f * (B0[(size_t)obc.x * mult] + B1p[(size_t)obc.y * mult] +
                     B2p[(size_t)obc.z * mult] + B3p[(size_t)obc.w * mult]) -
            Ck + pri[tid];

  // pipeline prime: e* = raw gathers for step t=1; obn = obs row 2
  int4 obn = obs4[1];
  float e0 = B0[(size_t)obn.x * mult], e1 = B1p[(size_t)obn.y * mult];
  float e2 = B2p[(size_t)obn.z * mult], e3 = B3p[(size_t)obn.w * mult];
  obn = obs4[2];   // rows 0..511 always allocated; 2 < Tq

  __syncthreads();  // pinned tiles visible

  const unsigned char* eb = (const unsigned char*)elds4;

  for (int t = 1; t < L; ++t) {
    // issue gathers for step t+1 (obn = obs row t+1, loaded last iter)
    const float en0 = B0[(size_t)obn.x * mult];
    const float en1 = B1p[(size_t)obn.y * mult];
    const float en2 = B2p[(size_t)obn.z * mult];
    const float en3 = B3p[(size_t)obn.w * mult];
    // refill obn with obs row t+2 (clamped; waste-but-valid near the tail)
    const int nr = (t + 2 < Tq) ? (t + 2) : (Tq - 1);
    obn = obs4[nr];

    // issue stream loads for tile 2 (s=0)
    uint4 ra0 = Eg4[2 * 2048 + 0 * 512 + tid];
    uint4 ra1 = Eg4[2 * 2048 + 1 * 512 + tid];
    uint4 ra2 = Eg4[2 * 2048 + 2 * 512 + tid];
    uint4 ra3 = Eg4[2 * 2048 + 3 * 512 + tid];
    uint4 rb0, rb1, rb2, rb3;

    // B1: block max of alpha
    float m = a;
#pragma unroll
    for (int o = 32; o; o >>= 1) m = fmaxf(m, __shfl_xor(m, o));
    if (lane == 0) red[wid] = m;
    __syncthreads();
    float M = red[0];
#pragma unroll
    for (int q = 1; q < 8; ++q) M = fmaxf(M, red[q]);

    w[tid] = expf(a - M);
    __syncthreads();  // B2: w published

    float acc[8];
#pragma unroll
    for (int q = 0; q < 8; ++q) acc[q] = 0.f;

    // compute one 64-row tile from LDS slot
#define COMP_TILE(TAU, SLOT)                                              \
    {                                                                     \
      const int jb = (TAU) * 64 + 8 * g;                                  \
      const unsigned char* sl = eb + (size_t)(SLOT) * 32768;              \
      _Pragma("unroll")                                                   \
      for (int jj = 0; jj < 8; ++jj) {                                    \
        const float wj = w[jb + jj];                                      \
        const uint2 e = *(const uint2*)&sl[(8 * g + jj) * 512 + 8 * i];   \
        floatx2 p;                                                        \
        p = __builtin_amdgcn_cvt_pk_f32_fp8(e.x, false);                  \
        acc[0] += wj * p.x;  acc[1] += wj * p.y;                          \
        p = __builtin_amdgcn_cvt_pk_f32_fp8(e.x, true);                   \
        acc[2] += wj * p.x;  acc[3] += wj * p.y;                          \
        p = __builtin_amdgcn_cvt_pk_f32_fp8(e.y, false);                  \
        acc[4] += wj * p.x;  acc[5] += wj * p.y;                          \
        p = __builtin_amdgcn_cvt_pk_f32_fp8(e.y, true);                   \
        acc[6] += wj * p.x;  acc[7] += wj * p.y;                          \
      }                                                                   \
    }

    // resident tiles; meanwhile write s=0 into slot 2 (loads arrive under B1/B2)
    COMP_TILE(0, 0);
    elds4[2 * 2048 + 0 * 512 + tid] = ra0;
    elds4[2 * 2048 + 1 * 512 + tid] = ra1;
    elds4[2 * 2048 + 2 * 512 + tid] = ra2;
    elds4[2 * 2048 + 3 * 512 + tid] = ra3;
    COMP_TILE(1, 1);
    __syncthreads();  // slot 2 ready

    // streamed tiles s=0..5 (tau = s+2, slot = 2+(s&1)), dbuf pipeline
    rb0 = Eg4[3 * 2048 + 0 * 512 + tid]; rb1 = Eg4[3 * 2048 + 1 * 512 + tid];
    rb2 = Eg4[3 * 2048 + 2 * 512 + tid]; rb3 = Eg4[3 * 2048 + 3 * 512 + tid];
    COMP_TILE(2, 2);
    elds4[3 * 2048 + 0 * 512 + tid] = rb0; elds4[3 * 2048 + 1 * 512 + tid] = rb1;
    elds4[3 * 2048 + 2 * 512 + tid] = rb2; elds4[3 * 2048 + 3 * 512 + tid] = rb3;
    __syncthreads();
    ra0 = Eg4[4 * 2048 + 0 * 512 + tid]; ra1 = Eg4[4 * 2048 + 1 * 512 + tid];
    ra2 = Eg4[4 * 2048 + 2 * 512 + tid]; ra3 = Eg4[4 * 2048 + 3 * 512 + tid];
    COMP_TILE(3, 3);
    elds4[2 * 2048 + 0 * 512 + tid] = ra0; elds4[2 * 2048 + 1 * 512 + tid] = ra1;
    elds4[2 * 2048 + 2 * 512 + tid] = ra2; elds4[2 * 2048 + 3 * 512 + tid] = ra3;
    __syncthreads();
    rb0 = Eg4[5 * 2048 + 0 * 512 + tid]; rb1 = Eg4[5 * 2048 + 1 * 512 + tid];
    rb2 = Eg4[5 * 2048 + 2 * 512 + tid]; rb3 = Eg4[5 * 2048 + 3 * 512 + tid];
    COMP_TILE(4, 2);
    elds4[3 * 2048 + 0 * 512 + tid] = rb0; elds4[3 * 2048 + 1 * 512 + tid] = rb1;
    elds4[3 * 2048 + 2 * 512 + tid] = rb2; elds4[3 * 2048 + 3 * 512 + tid] = rb3;
    __syncthreads();
    ra0 = Eg4[6 * 2048 + 0 * 512 + tid]; ra1 = Eg4[6 * 2048 + 1 * 512 + tid];
    ra2 = Eg4[6 * 2048 + 2 * 512 + tid]; ra3 = Eg4[6 * 2048 + 3 * 512 + tid];
    COMP_TILE(5, 3);
    elds4[2 * 2048 + 0 * 512 + tid] = ra0; elds4[2 * 2048 + 1 * 512 + tid] = ra1;
    elds4[2 * 2048 + 2 * 512 + tid] = ra2; elds4[2 * 2048 + 3 * 512 + tid] = ra3;
    __syncthreads();
    rb0 = Eg4[7 * 2048 + 0 * 512 + tid]; rb1 = Eg4[7 * 2048 + 1 * 512 + tid];
    rb2 = Eg4[7 * 2048 + 2 * 512 + tid]; rb3 = Eg4[7 * 2048 + 3 * 512 + tid];
    COMP_TILE(6, 2);
    elds4[3 * 2048 + 0 * 512 + tid] = rb0; elds4[3 * 2048 + 1 * 512 + tid] = rb1;
    elds4[3 * 2048 + 2 * 512 + tid] = rb2; elds4[3 * 2048 + 3 * 512 + tid] = rb3;
    __syncthreads();
    COMP_TILE(7, 3);
    *(float4*)&part[g][8 * i] = float4{acc[0], acc[1], acc[2], acc[3]};
    *(float4*)&part[g][8 * i + 4] = float4{acc[4], acc[5], acc[6], acc[7]};
    __syncthreads();  // B3

    float ssum = 0.f;
#pragma unroll
    for (int gg = 0; gg < 8; ++gg) ssum += part[gg][tid];
    // consume last-iteration's raw gathers (latency fully hidden)
    const float emt = 0.25f * (e0 + e1 + e2 + e3) - Ck;
    a = emt + M + logf(ssum) - LOG_E_SCALE;
    e0 = en0; e1 = en1; e2 = en2; e3 = en3;
#undef COMP_TILE
  }

  // out[b] = logsumexp_k a
  float m = a;
#pragma unroll
  for (int o = 32; o; o >>= 1) m = fmaxf(m, __shfl_xor(m, o));
  if (lane == 0) red[wid] = m;
  __syncthreads();
  float M = red[0];
#pragma unroll
  for (int q = 1; q < 8; ++q) M = fmaxf(M, red[q]);
  float e = expf(a - M);
#pragma unroll
  for (int o = 32; o; o >>= 1) e += __shfl_xor(e, o);
  if (lane == 0) red[8 + wid] = e;
  __syncthreads();
  if (tid == 0) {
    float S = 0.f;
#pragma unroll
    for (int q = 0; q < 8; ++q) S += red[8 + q];
    out[b] = M + logf(S);
  }
}

// ---------------------------------------------------------------------------
// Workspace layout (bytes):
//   E8  : [0, 262144)                 fp8 1024*softmax(tran)  256 KB
//   Z   : [262144, 270336)            per-(s,h) row LSE       8 KB
//   C   : [270336, 272384)            emission constant       2 KB
//   UT  : [272384, 272384+81920000)   transposed table        81.9 MB
// ---------------------------------------------------------------------------
extern "C" void kernel_launch(void* const* d_in, const int* in_sizes, int n_in,
                              void* d_out, int out_size, void* d_ws,
                              size_t ws_size, hipStream_t stream) {
  const int* obs = (const int*)d_in[0];
  const int* lengths = (const int*)d_in[1];
  const float* U = (const float*)d_in[2];       // unnormalized_emis (S,H,V)
  const float* tran = (const float*)d_in[3];    // unnormalized_tran (H,H)
  const float* pri = (const float*)d_in[4];     // log_state_priors (H,)
  float* out = (float*)d_out;

  char* ws = (char*)d_ws;
  unsigned int* E8 = (unsigned int*)ws;
  float* Z = (float*)(ws + 262144);
  float* C = (float*)(ws + 270336);
  float* UT = (float*)(ws + 272384);

  const size_t need_ut_bytes = 272384ull + 81920000ull;
  const int use_ut = (ws_size >= need_ut_bytes) ? 1 : 0;

  k_row_lse<<<Sq * Hq, 256, 0, stream>>>(U, Z);
  k_cvec<<<1, 512, 0, stream>>>(Z, C);
  k_tran_softmax<<<Hq, 512, 0, stream>>>(tran, E8);
  if (use_ut) {
    dim3 grid((Vq + 31) / 32, Hq / 32, Sq);
    k_transpose<<<grid, dim3(32, 8), 0, stream>>>(U, UT);
  }
  k_forward<<<Bq, 512, 0, stream>>>(obs, lengths, U, UT, C, E8, pri, out,
                                    use_ut);
}